// Round 1
// baseline (184.091 us; speedup 1.0000x reference)
//
#include <hip/hip_runtime.h>
#include <math.h>

static constexpr int S_LEN = 2048;
static constexpr int KMIX  = 20;
static constexpr int NROWS = 256 * 2048;          // B*S
static constexpr int BLOCK = 256;
static constexpr int NBLK  = NROWS / BLOCK;       // 2048
static constexpr float SIGMA_MIN_F = 0.01f;
static constexpr float LOG_2PI_F   = 1.8378770664093453f;

__global__ __launch_bounds__(BLOCK) void sketch_loss_kernel(
    const float* __restrict__ xs,
    const float* __restrict__ logits,
    const float* __restrict__ mus,
    const float* __restrict__ sxp,
    const float* __restrict__ syp,
    const float* __restrict__ sxyp,
    const float* __restrict__ pen,
    float* __restrict__ partials)
{
    const int r = blockIdx.x * BLOCK + threadIdx.x;   // one row per thread, grid exact

    float acc_pos, acc_pen;
    {
        const int s = r & (S_LEN - 1);
        const float* xr = xs + (size_t)r * 5;
        const float x0 = xr[0], x1 = xr[1];
        const float pt0 = xr[2], pt1 = xr[3], pt2 = xr[4];
        const int rn = (s == S_LEN - 1) ? (r - (S_LEN - 1)) : (r + 1);
        const float* xnr = xs + (size_t)rn * 5;
        const float rel0 = xnr[0] - x0;
        const float rel1 = xnr[1] - x1;

        const float4* lg4  = (const float4*)(logits + (size_t)r * KMIX);
        const float4* sx4  = (const float4*)(sxp    + (size_t)r * KMIX);
        const float4* sy4  = (const float4*)(syp    + (size_t)r * KMIX);
        const float4* sxy4 = (const float4*)(sxyp   + (size_t)r * KMIX);
        const float4* mu4  = (const float4*)(mus    + (size_t)r * KMIX * 2);

        float m_a = -INFINITY, s_a = 0.0f;   // online LSE of logits + comp_logp
        float m_l = -INFINITY, s_l = 0.0f;   // online LSE of logits

        #pragma unroll
        for (int c = 0; c < KMIX / 4; ++c) {
            const float4 l4 = lg4[c];
            const float4 x4 = sx4[c];
            const float4 y4 = sy4[c];
            const float4 w4 = sxy4[c];
            const float4 mA = mu4[2 * c];
            const float4 mB = mu4[2 * c + 1];

            const float lv[4]  = {l4.x, l4.y, l4.z, l4.w};
            const float sxa[4] = {x4.x, x4.y, x4.z, x4.w};
            const float sya[4] = {y4.x, y4.y, y4.z, y4.w};
            const float swa[4] = {w4.x, w4.y, w4.z, w4.w};
            const float mu_[8] = {mA.x, mA.y, mA.z, mA.w, mB.x, mB.y, mB.z, mB.w};

            float av[4];
            #pragma unroll
            for (int j = 0; j < 4; ++j) {
                const float sx  = fmaxf(sxa[j], SIGMA_MIN_F);
                const float sy  = fmaxf(sya[j], SIGMA_MIN_F);
                const float sxy = fminf(fmaxf(swa[j], -SIGMA_MIN_F), SIGMA_MIN_F);
                const float d1 = rel0 - mu_[2 * j];
                const float d2 = rel1 - mu_[2 * j + 1];
                const float z1 = d1 / sx;
                const float z2 = (d2 - sxy * z1) / sy;
                av[j] = lv[j] - 0.5f * (z1 * z1 + z2 * z2) - LOG_2PI_F - __logf(sx * sy);
            }

            const float cma = fmaxf(fmaxf(av[0], av[1]), fmaxf(av[2], av[3]));
            if (cma > m_a) { s_a *= __expf(m_a - cma); m_a = cma; }
            s_a += __expf(av[0] - m_a) + __expf(av[1] - m_a)
                 + __expf(av[2] - m_a) + __expf(av[3] - m_a);

            const float cml = fmaxf(fmaxf(lv[0], lv[1]), fmaxf(lv[2], lv[3]));
            if (cml > m_l) { s_l *= __expf(m_l - cml); m_l = cml; }
            s_l += __expf(lv[0] - m_l) + __expf(lv[1] - m_l)
                 + __expf(lv[2] - m_l) + __expf(lv[3] - m_l);
        }

        acc_pos = (m_a + __logf(s_a)) - (m_l + __logf(s_l));   // logp for this row

        const float* pr = pen + (size_t)r * 3;
        const float q0 = pr[0], q1 = pr[1], q2 = pr[2];
        const float mq = fmaxf(fmaxf(q0, q1), q2);
        const float lseq = mq + __logf(__expf(q0 - mq) + __expf(q1 - mq) + __expf(q2 - mq));
        acc_pen = pt0 * (q0 - lseq) + pt1 * (q1 - lseq) + pt2 * (q2 - lseq);
    }

    // ---- block reduction (wave shuffle + LDS across 4 waves) ----
    const int lane = threadIdx.x & 63;
    const int wid  = threadIdx.x >> 6;
    #pragma unroll
    for (int off = 32; off > 0; off >>= 1) {
        acc_pos += __shfl_down(acc_pos, off, 64);
        acc_pen += __shfl_down(acc_pen, off, 64);
    }
    __shared__ float s_pos[4], s_pen[4];
    if (lane == 0) { s_pos[wid] = acc_pos; s_pen[wid] = acc_pen; }
    __syncthreads();
    if (threadIdx.x == 0) {
        partials[blockIdx.x * 2 + 0] = s_pos[0] + s_pos[1] + s_pos[2] + s_pos[3];
        partials[blockIdx.x * 2 + 1] = s_pen[0] + s_pen[1] + s_pen[2] + s_pen[3];
    }
}

__global__ __launch_bounds__(BLOCK) void sketch_reduce_kernel(
    const float* __restrict__ partials, float* __restrict__ out)
{
    float tp = 0.0f, te = 0.0f;
    for (int i = threadIdx.x; i < NBLK; i += BLOCK) {
        tp += partials[2 * i + 0];
        te += partials[2 * i + 1];
    }
    #pragma unroll
    for (int off = 32; off > 0; off >>= 1) {
        tp += __shfl_down(tp, off, 64);
        te += __shfl_down(te, off, 64);
    }
    __shared__ float sp[4], se[4];
    const int lane = threadIdx.x & 63;
    const int wid  = threadIdx.x >> 6;
    if (lane == 0) { sp[wid] = tp; se[wid] = te; }
    __syncthreads();
    if (threadIdx.x == 0) {
        const float P = sp[0] + sp[1] + sp[2] + sp[3];
        const float E = se[0] + se[1] + se[2] + se[3];
        out[0] = -P / (float)NROWS;
        out[1] = -E / (float)NROWS;
    }
}

extern "C" void kernel_launch(void* const* d_in, const int* in_sizes, int n_in,
                              void* d_out, int out_size, void* d_ws, size_t ws_size,
                              hipStream_t stream) {
    const float* xs     = (const float*)d_in[0];
    const float* logits = (const float*)d_in[1];
    const float* mus    = (const float*)d_in[2];
    const float* sx     = (const float*)d_in[3];
    const float* sy     = (const float*)d_in[4];
    const float* sxy    = (const float*)d_in[5];
    const float* pen    = (const float*)d_in[6];
    float* out = (float*)d_out;
    float* partials = (float*)d_ws;          // NBLK * 2 floats = 16 KiB

    sketch_loss_kernel<<<NBLK, BLOCK, 0, stream>>>(xs, logits, mus, sx, sy, sxy, pen, partials);
    sketch_reduce_kernel<<<1, BLOCK, 0, stream>>>(partials, out);
}

// Round 2
// 48.373 us; speedup vs baseline: 3.8057x; 3.8057x over previous
//
#include <hip/hip_runtime.h>
#include <math.h>

static constexpr int S_LEN = 2048;
static constexpr int KMIX  = 20;
static constexpr int NROWS = 256 * 2048;          // B*S
static constexpr int BLOCK = 256;
static constexpr int NBLK  = NROWS / BLOCK;       // 2048
static constexpr float SIGMA_MIN_F = 0.01f;
static constexpr float LOG_2PI_F   = 1.8378770664093453f;

__global__ __launch_bounds__(BLOCK) void sketch_loss_kernel(
    const float* __restrict__ xs,
    const float* __restrict__ logits,
    const float* __restrict__ mus,
    const float* __restrict__ sxp,
    const float* __restrict__ syp,
    const float* __restrict__ sxyp,
    const float* __restrict__ pen,
    float* __restrict__ partials)
{
    const int r = blockIdx.x * BLOCK + threadIdx.x;   // one row per thread, grid exact

    // ---------------- hoisted loads: issue EVERYTHING up front ----------------
    const float4* lg4  = (const float4*)(logits + (size_t)r * KMIX);
    const float4* sx4  = (const float4*)(sxp    + (size_t)r * KMIX);
    const float4* sy4  = (const float4*)(syp    + (size_t)r * KMIX);
    const float4* sxy4 = (const float4*)(sxyp   + (size_t)r * KMIX);
    const float4* mu4  = (const float4*)(mus    + (size_t)r * KMIX * 2);

    float4 L[5], X[5], Y[5], W[5], MA[5], MB[5];
    #pragma unroll
    for (int c = 0; c < 5; ++c) L[c] = lg4[c];
    #pragma unroll
    for (int c = 0; c < 5; ++c) X[c] = sx4[c];
    #pragma unroll
    for (int c = 0; c < 5; ++c) Y[c] = sy4[c];
    #pragma unroll
    for (int c = 0; c < 5; ++c) W[c] = sxy4[c];
    #pragma unroll
    for (int c = 0; c < 5; ++c) { MA[c] = mu4[2 * c]; MB[c] = mu4[2 * c + 1]; }

    const int s = r & (S_LEN - 1);
    const float* xr = xs + (size_t)r * 5;
    const float x0 = xr[0], x1 = xr[1];
    const float pt0 = xr[2], pt1 = xr[3], pt2 = xr[4];
    const int rn = (s == S_LEN - 1) ? (r - (S_LEN - 1)) : (r + 1);
    const float* xnr = xs + (size_t)rn * 5;
    const float xn0 = xnr[0], xn1 = xnr[1];

    const float* pr = pen + (size_t)r * 3;
    const float q0 = pr[0], q1 = pr[1], q2 = pr[2];

    // pin: no compute may be scheduled before this point, loads stay clustered
    __builtin_amdgcn_sched_barrier(0);

    // ---------------- compute ----------------
    const float rel0 = xn0 - x0;
    const float rel1 = xn1 - x1;

    float m_a = -INFINITY, s_a = 0.0f;   // online LSE of logits + comp_logp
    float m_l = -INFINITY, s_l = 0.0f;   // online LSE of logits

    #pragma unroll
    for (int c = 0; c < 5; ++c) {
        const float lv[4]  = {L[c].x, L[c].y, L[c].z, L[c].w};
        const float sxa[4] = {X[c].x, X[c].y, X[c].z, X[c].w};
        const float sya[4] = {Y[c].x, Y[c].y, Y[c].z, Y[c].w};
        const float swa[4] = {W[c].x, W[c].y, W[c].z, W[c].w};
        const float mu_[8] = {MA[c].x, MA[c].y, MA[c].z, MA[c].w,
                              MB[c].x, MB[c].y, MB[c].z, MB[c].w};

        float av[4];
        #pragma unroll
        for (int j = 0; j < 4; ++j) {
            const float sx  = fmaxf(sxa[j], SIGMA_MIN_F);
            const float sy  = fmaxf(sya[j], SIGMA_MIN_F);
            const float sxy = fminf(fmaxf(swa[j], -SIGMA_MIN_F), SIGMA_MIN_F);
            const float d1 = rel0 - mu_[2 * j];
            const float d2 = rel1 - mu_[2 * j + 1];
            const float z1 = d1 / sx;
            const float z2 = (d2 - sxy * z1) / sy;
            av[j] = lv[j] - 0.5f * (z1 * z1 + z2 * z2) - LOG_2PI_F - __logf(sx * sy);
        }

        const float cma = fmaxf(fmaxf(av[0], av[1]), fmaxf(av[2], av[3]));
        if (cma > m_a) { s_a *= __expf(m_a - cma); m_a = cma; }
        s_a += __expf(av[0] - m_a) + __expf(av[1] - m_a)
             + __expf(av[2] - m_a) + __expf(av[3] - m_a);

        const float cml = fmaxf(fmaxf(lv[0], lv[1]), fmaxf(lv[2], lv[3]));
        if (cml > m_l) { s_l *= __expf(m_l - cml); m_l = cml; }
        s_l += __expf(lv[0] - m_l) + __expf(lv[1] - m_l)
             + __expf(lv[2] - m_l) + __expf(lv[3] - m_l);
    }

    float acc_pos = (m_a + __logf(s_a)) - (m_l + __logf(s_l));   // logp for this row

    const float mq = fmaxf(fmaxf(q0, q1), q2);
    const float lseq = mq + __logf(__expf(q0 - mq) + __expf(q1 - mq) + __expf(q2 - mq));
    float acc_pen = pt0 * (q0 - lseq) + pt1 * (q1 - lseq) + pt2 * (q2 - lseq);

    // ---- block reduction (wave shuffle + LDS across 4 waves) ----
    const int lane = threadIdx.x & 63;
    const int wid  = threadIdx.x >> 6;
    #pragma unroll
    for (int off = 32; off > 0; off >>= 1) {
        acc_pos += __shfl_down(acc_pos, off, 64);
        acc_pen += __shfl_down(acc_pen, off, 64);
    }
    __shared__ float s_pos[4], s_pen[4];
    if (lane == 0) { s_pos[wid] = acc_pos; s_pen[wid] = acc_pen; }
    __syncthreads();
    if (threadIdx.x == 0) {
        partials[blockIdx.x * 2 + 0] = s_pos[0] + s_pos[1] + s_pos[2] + s_pos[3];
        partials[blockIdx.x * 2 + 1] = s_pen[0] + s_pen[1] + s_pen[2] + s_pen[3];
    }
}

__global__ __launch_bounds__(BLOCK) void sketch_reduce_kernel(
    const float* __restrict__ partials, float* __restrict__ out)
{
    float tp = 0.0f, te = 0.0f;
    for (int i = threadIdx.x; i < NBLK; i += BLOCK) {
        tp += partials[2 * i + 0];
        te += partials[2 * i + 1];
    }
    #pragma unroll
    for (int off = 32; off > 0; off >>= 1) {
        tp += __shfl_down(tp, off, 64);
        te += __shfl_down(te, off, 64);
    }
    __shared__ float sp[4], se[4];
    const int lane = threadIdx.x & 63;
    const int wid  = threadIdx.x >> 6;
    if (lane == 0) { sp[wid] = tp; se[wid] = te; }
    __syncthreads();
    if (threadIdx.x == 0) {
        const float P = sp[0] + sp[1] + sp[2] + sp[3];
        const float E = se[0] + se[1] + se[2] + se[3];
        out[0] = -P / (float)NROWS;
        out[1] = -E / (float)NROWS;
    }
}

extern "C" void kernel_launch(void* const* d_in, const int* in_sizes, int n_in,
                              void* d_out, int out_size, void* d_ws, size_t ws_size,
                              hipStream_t stream) {
    const float* xs     = (const float*)d_in[0];
    const float* logits = (const float*)d_in[1];
    const float* mus    = (const float*)d_in[2];
    const float* sx     = (const float*)d_in[3];
    const float* sy     = (const float*)d_in[4];
    const float* sxy    = (const float*)d_in[5];
    const float* pen    = (const float*)d_in[6];
    float* out = (float*)d_out;
    float* partials = (float*)d_ws;          // NBLK * 2 floats = 16 KiB

    sketch_loss_kernel<<<NBLK, BLOCK, 0, stream>>>(xs, logits, mus, sx, sy, sxy, pen, partials);
    sketch_reduce_kernel<<<1, BLOCK, 0, stream>>>(partials, out);
}